// Round 1
// baseline (405.829 us; speedup 1.0000x reference)
//
#include <hip/hip_runtime.h>

#define NPIX   65536          // B*H*W
#define CCH    64
#define KCODE  1024
#define HW     4096
#define Q_ELEMS 4194304
#define LOSS0_OFF 4194304
#define LOSS1_OFF 4194305
#define IDX_OFF   4194306
#define PTILE  16             // pixels per block

// numpy pairwise_sum middle branch for n=64 on squares (bit-exact np.sum(x*x))
template <typename F>
__device__ __forceinline__ float np_pairwise64_sq(F v) {
    float r[8];
#pragma unroll
    for (int j = 0; j < 8; ++j) r[j] = __fmul_rn(v(j), v(j));
#pragma unroll
    for (int i = 8; i < 64; i += 8) {
#pragma unroll
        for (int j = 0; j < 8; ++j)
            r[j] = __fadd_rn(r[j], __fmul_rn(v(i + j), v(i + j)));
    }
    return __fadd_rn(
        __fadd_rn(__fadd_rn(r[0], r[1]), __fadd_rn(r[2], r[3])),
        __fadd_rn(__fadd_rn(r[4], r[5]), __fadd_rn(r[6], r[7])));
}

// prep: transpose emb -> et[c][k], se[k] = np.sum(emb[k]^2), zero loss slots
__global__ void prep_kernel(const float* __restrict__ emb,
                            float* __restrict__ se, float* __restrict__ et,
                            float* __restrict__ out) {
    const int tid = blockIdx.x * 256 + threadIdx.x;   // 0..65535
    const int c = tid >> 10, k = tid & 1023;
    et[tid] = emb[k * CCH + c];                        // coalesced write
    if (tid < KCODE) {
        const float* e = emb + (size_t)tid * CCH;
        se[tid] = np_pairwise64_sq([&](int i) { return e[i]; });
    }
    if (tid == 0) { out[LOSS0_OFF] = 0.f; out[LOSS1_OFF] = 0.f; }
}

// main: block = 256 thr = 4 waves; lanes = codes; 16 pixels per block.
// LDS cut to ~18.7KB (shfl pre-reduction) -> 8 blocks/CU, 32 waves/CU.
__launch_bounds__(256, 8)
__global__ void vq_kernel(const float* __restrict__ z,
                          const float* __restrict__ emb,
                          const float* __restrict__ se,
                          const float* __restrict__ et,
                          float* __restrict__ out) {
    __shared__ float s_szz[PTILE];
    __shared__ unsigned long long s_cand[PTILE][129];  // halved via shfl pre-reduce; +pad
    __shared__ unsigned long long s_part[PTILE][16];
    __shared__ unsigned int s_k[PTILE];
    __shared__ float s_red[4];

    const int t    = threadIdx.x;
    const int lane = t & 63;
    const int wave = t >> 6;
    const int pg0  = blockIdx.x * PTILE;
    const int b    = pg0 >> 12;
    const int hw0  = pg0 & 4095;
    const float* zb = z + (size_t)b * CCH * HW + hw0;  // zb[c*HW + p], wave-uniform

    // szz for the block's 16 pixels (np order), lanes 0..15 of wave 0
    if (t < PTILE)
        s_szz[t] = np_pairwise64_sq([&](int i) { return zb[(size_t)i * HW + t]; });
    __syncthreads();

    float szzv[PTILE];
#pragma unroll
    for (int p = 0; p < PTILE; ++p) szzv[p] = s_szz[p];

    unsigned long long best[PTILE];
#pragma unroll
    for (int p = 0; p < PTILE; ++p) best[p] = ~0ULL;

    for (int j = 0; j < 4; ++j) {
        const int kk = ((wave << 2) + j) * 64 + lane;   // this thread's code
        const float sek = se[kk];                        // coalesced VGPR load
        const float* ecol = et + kk;
        float acc[PTILE];
#pragma unroll
        for (int p = 0; p < PTILE; ++p) acc[p] = 0.f;

#pragma unroll 8
        for (int c = 0; c < CCH; ++c) {
            const float ev = ecol[c << 10];              // E^T[c][kk], 256B/wave
            float zrow[PTILE];                            // 16 uniform scalars -> s_load_dwordx16
#pragma unroll
            for (int p = 0; p < PTILE; ++p) zrow[p] = zb[(size_t)c * HW + p];
#pragma unroll
            for (int p = 0; p < PTILE; ++p)
                acc[p] = __builtin_fmaf(zrow[p], ev, acc[p]);  // same chain as R2
        }

#pragma unroll
        for (int p = 0; p < PTILE; ++p) {
            // d = fl( fl(szz+se) - 2*dot )  (identical algebra to R2, absmax 0)
            float d = __fsub_rn(__fadd_rn(szzv[p], sek), __fadd_rn(acc[p], acc[p]));
            unsigned long long cand =
                ((unsigned long long)__float_as_uint(d) << 32) | (unsigned)kk;
            best[p] = cand < best[p] ? cand : best[p];   // d>0 -> bit-order == value-order
        }
    }

    // stage 1.5: one butterfly step in registers (exact: u64 min over same set),
    // halves the LDS candidate buffer -> occupancy 4 -> 8 blocks/CU
#pragma unroll
    for (int p = 0; p < PTILE; ++p) {
        unsigned long long o = __shfl_xor(best[p], 1, 64);
        best[p] = o < best[p] ? o : best[p];
    }
    if ((t & 1) == 0) {
#pragma unroll
        for (int p = 0; p < PTILE; ++p) s_cand[p][t >> 1] = best[p];
    }
    __syncthreads();

    {   // stage 2: 256 threads, each folds 8 of the 128 candidates of pixel t&15
        const int p = t & 15, g = t >> 4;
        unsigned long long m = s_cand[p][(g << 3)];
#pragma unroll
        for (int u = 1; u < 8; ++u) {
            unsigned long long v = s_cand[p][(g << 3) + u];
            m = v < m ? v : m;
        }
        s_part[p][g] = m;
    }
    __syncthreads();

    if (t < PTILE) {   // stage 3: final per-pixel min; packed low bits = first-index k
        unsigned long long m = s_part[t][0];
#pragma unroll
        for (int g = 1; g < 16; ++g) {
            unsigned long long v = s_part[t][g];
            m = v < m ? v : m;
        }
        const unsigned int k = (unsigned int)m;
        s_k[t] = k;
        out[IDX_OFF + pg0 + t] = (float)k;
    }
    __syncthreads();

    // epilogue: thread t -> pixel p=t&15, channels c = (t>>4) + 16u
    float lsum = 0.f;
    {
        const int p = t & 15, g = t >> 4;
        const int k = (int)s_k[p];
#pragma unroll
        for (int u = 0; u < 4; ++u) {
            const int c = g + (u << 4);
            float e    = emb[(size_t)k * CCH + c];
            float zc   = zb[(size_t)c * HW + p];
            float diff = __fsub_rn(e, zc);               // STE rounding as in R2
            out[((size_t)(b * CCH + c)) * HW + hw0 + p] = __fadd_rn(zc, diff);
            lsum = __builtin_fmaf(diff, diff, lsum);
        }
    }
#pragma unroll
    for (int off = 32; off > 0; off >>= 1) lsum += __shfl_down(lsum, off, 64);
    if (lane == 0) s_red[wave] = lsum;
    __syncthreads();
    if (t == 0) {
        float v = (s_red[0] + s_red[1] + s_red[2] + s_red[3]) * (1.0f / (float)Q_ELEMS);
        atomicAdd(out + LOSS0_OFF, v);   // codebook_loss
        atomicAdd(out + LOSS1_OFF, v);   // commitment_loss (same forward value)
    }
}

extern "C" void kernel_launch(void* const* d_in, const int* in_sizes, int n_in,
                              void* d_out, int out_size, void* d_ws, size_t ws_size,
                              hipStream_t stream) {
    const float* z   = (const float*)d_in[0];
    const float* emb = (const float*)d_in[1];
    float* out = (float*)d_out;
    float* se  = (float*)d_ws;                 // 1024 floats
    float* et  = se + KCODE;                   // 65536 floats (E^T)

    prep_kernel<<<dim3(256), dim3(256), 0, stream>>>(emb, se, et, out);
    vq_kernel<<<dim3(NPIX / PTILE), dim3(256), 0, stream>>>(z, emb, se, et, out);
}

// Round 2
// 218.598 us; speedup vs baseline: 1.8565x; 1.8565x over previous
//
#include <hip/hip_runtime.h>

#define NPIX   65536          // B*H*W
#define CCH    64
#define KCODE  1024
#define HW     4096
#define Q_ELEMS 4194304
#define LOSS0_OFF 4194304
#define LOSS1_OFF 4194305
#define IDX_OFF   4194306
#define PTILE  16             // pixels per block

// numpy pairwise_sum middle branch for n=64 on squares (bit-exact np.sum(x*x))
template <typename F>
__device__ __forceinline__ float np_pairwise64_sq(F v) {
    float r[8];
#pragma unroll
    for (int j = 0; j < 8; ++j) r[j] = __fmul_rn(v(j), v(j));
#pragma unroll
    for (int i = 8; i < 64; i += 8) {
#pragma unroll
        for (int j = 0; j < 8; ++j)
            r[j] = __fadd_rn(r[j], __fmul_rn(v(i + j), v(i + j)));
    }
    return __fadd_rn(
        __fadd_rn(__fadd_rn(r[0], r[1]), __fadd_rn(r[2], r[3])),
        __fadd_rn(__fadd_rn(r[4], r[5]), __fadd_rn(r[6], r[7])));
}

// prep: transpose emb -> et[c][k], se[k] = np.sum(emb[k]^2), zero loss slots
__global__ void prep_kernel(const float* __restrict__ emb,
                            float* __restrict__ se, float* __restrict__ et,
                            float* __restrict__ out) {
    const int tid = blockIdx.x * 256 + threadIdx.x;   // 0..65535
    const int c = tid >> 10, k = tid & 1023;
    et[tid] = emb[k * CCH + c];                        // coalesced write
    if (tid < KCODE) {
        const float* e = emb + (size_t)tid * CCH;
        se[tid] = np_pairwise64_sq([&](int i) { return e[i]; });
    }
    if (tid == 0) { out[LOSS0_OFF] = 0.f; out[LOSS1_OFF] = 0.f; }
}

// main: block = 256 thr = 4 waves; lanes = codes; 16 pixels per block.
// LDS ~18.7KB (shfl pre-reduction) -> 8 blocks/CU possible; launch_bounds kept
// at (256,4) so the allocator stays at ~56 VGPR (<=64 => 8 waves/SIMD naturally).
// R1 lesson: forcing (256,8) squeezed VGPR to 32 -> scratch spills (FETCH 23x).
__launch_bounds__(256, 4)
__global__ void vq_kernel(const float* __restrict__ z,
                          const float* __restrict__ emb,
                          const float* __restrict__ se,
                          const float* __restrict__ et,
                          float* __restrict__ out) {
    __shared__ float s_szz[PTILE];
    __shared__ unsigned long long s_cand[PTILE][129];  // halved via shfl pre-reduce; +pad
    __shared__ unsigned long long s_part[PTILE][16];
    __shared__ unsigned int s_k[PTILE];
    __shared__ float s_red[4];

    const int t    = threadIdx.x;
    const int lane = t & 63;
    const int wave = t >> 6;
    const int pg0  = blockIdx.x * PTILE;
    const int b    = pg0 >> 12;
    const int hw0  = pg0 & 4095;
    const float* zb = z + (size_t)b * CCH * HW + hw0;  // zb[c*HW + p], wave-uniform

    // szz for the block's 16 pixels (np order), lanes 0..15 of wave 0
    if (t < PTILE)
        s_szz[t] = np_pairwise64_sq([&](int i) { return zb[(size_t)i * HW + t]; });
    __syncthreads();

    float szzv[PTILE];
#pragma unroll
    for (int p = 0; p < PTILE; ++p) szzv[p] = s_szz[p];

    unsigned long long best[PTILE];
#pragma unroll
    for (int p = 0; p < PTILE; ++p) best[p] = ~0ULL;

    for (int j = 0; j < 4; ++j) {
        const int kk = ((wave << 2) + j) * 64 + lane;   // this thread's code
        const float sek = se[kk];                        // coalesced VGPR load
        const float* ecol = et + kk;
        float acc[PTILE];
#pragma unroll
        for (int p = 0; p < PTILE; ++p) acc[p] = 0.f;

#pragma unroll 8
        for (int c = 0; c < CCH; ++c) {
            const float ev = ecol[c << 10];              // E^T[c][kk], 256B/wave
            float zrow[PTILE];                            // 16 uniform scalars -> s_load_dwordx16
#pragma unroll
            for (int p = 0; p < PTILE; ++p) zrow[p] = zb[(size_t)c * HW + p];
#pragma unroll
            for (int p = 0; p < PTILE; ++p)
                acc[p] = __builtin_fmaf(zrow[p], ev, acc[p]);  // same chain as R2
        }

#pragma unroll
        for (int p = 0; p < PTILE; ++p) {
            // d = fl( fl(szz+se) - 2*dot )  (identical algebra to R2, absmax 0)
            float d = __fsub_rn(__fadd_rn(szzv[p], sek), __fadd_rn(acc[p], acc[p]));
            unsigned long long cand =
                ((unsigned long long)__float_as_uint(d) << 32) | (unsigned)kk;
            best[p] = cand < best[p] ? cand : best[p];   // d>0 -> bit-order == value-order
        }
    }

    // stage 1.5: one butterfly step in registers (exact: u64 min over same set),
    // halves the LDS candidate buffer -> 18.9KB total
#pragma unroll
    for (int p = 0; p < PTILE; ++p) {
        unsigned long long o = __shfl_xor(best[p], 1, 64);
        best[p] = o < best[p] ? o : best[p];
    }
    if ((t & 1) == 0) {
#pragma unroll
        for (int p = 0; p < PTILE; ++p) s_cand[p][t >> 1] = best[p];
    }
    __syncthreads();

    {   // stage 2: 256 threads, each folds 8 of the 128 candidates of pixel t&15
        const int p = t & 15, g = t >> 4;
        unsigned long long m = s_cand[p][(g << 3)];
#pragma unroll
        for (int u = 1; u < 8; ++u) {
            unsigned long long v = s_cand[p][(g << 3) + u];
            m = v < m ? v : m;
        }
        s_part[p][g] = m;
    }
    __syncthreads();

    if (t < PTILE) {   // stage 3: final per-pixel min; packed low bits = first-index k
        unsigned long long m = s_part[t][0];
#pragma unroll
        for (int g = 1; g < 16; ++g) {
            unsigned long long v = s_part[t][g];
            m = v < m ? v : m;
        }
        const unsigned int k = (unsigned int)m;
        s_k[t] = k;
        out[IDX_OFF + pg0 + t] = (float)k;
    }
    __syncthreads();

    // epilogue: thread t -> pixel p=t&15, channels c = (t>>4) + 16u
    float lsum = 0.f;
    {
        const int p = t & 15, g = t >> 4;
        const int k = (int)s_k[p];
#pragma unroll
        for (int u = 0; u < 4; ++u) {
            const int c = g + (u << 4);
            float e    = emb[(size_t)k * CCH + c];
            float zc   = zb[(size_t)c * HW + p];
            float diff = __fsub_rn(e, zc);               // STE rounding as in R2
            out[((size_t)(b * CCH + c)) * HW + hw0 + p] = __fadd_rn(zc, diff);
            lsum = __builtin_fmaf(diff, diff, lsum);
        }
    }
#pragma unroll
    for (int off = 32; off > 0; off >>= 1) lsum += __shfl_down(lsum, off, 64);
    if (lane == 0) s_red[wave] = lsum;
    __syncthreads();
    if (t == 0) {
        float v = (s_red[0] + s_red[1] + s_red[2] + s_red[3]) * (1.0f / (float)Q_ELEMS);
        atomicAdd(out + LOSS0_OFF, v);   // codebook_loss
        atomicAdd(out + LOSS1_OFF, v);   // commitment_loss (same forward value)
    }
}

extern "C" void kernel_launch(void* const* d_in, const int* in_sizes, int n_in,
                              void* d_out, int out_size, void* d_ws, size_t ws_size,
                              hipStream_t stream) {
    const float* z   = (const float*)d_in[0];
    const float* emb = (const float*)d_in[1];
    float* out = (float*)d_out;
    float* se  = (float*)d_ws;                 // 1024 floats
    float* et  = se + KCODE;                   // 65536 floats (E^T)

    prep_kernel<<<dim3(256), dim3(256), 0, stream>>>(emb, se, et, out);
    vq_kernel<<<dim3(NPIX / PTILE), dim3(256), 0, stream>>>(z, emb, se, et, out);
}

// Round 3
// 190.546 us; speedup vs baseline: 2.1298x; 1.1472x over previous
//
#include <hip/hip_runtime.h>

#define NPIX   65536          // B*H*W
#define CCH    64
#define KCODE  1024
#define HW     4096
#define Q_ELEMS 4194304
#define LOSS0_OFF 4194304
#define LOSS1_OFF 4194305
#define IDX_OFF   4194306
#define PTILE  16             // pixels per block

// numpy pairwise_sum middle branch for n=64 on squares (bit-exact np.sum(x*x))
template <typename F>
__device__ __forceinline__ float np_pairwise64_sq(F v) {
    float r[8];
#pragma unroll
    for (int j = 0; j < 8; ++j) r[j] = __fmul_rn(v(j), v(j));
#pragma unroll
    for (int i = 8; i < 64; i += 8) {
#pragma unroll
        for (int j = 0; j < 8; ++j)
            r[j] = __fadd_rn(r[j], __fmul_rn(v(i + j), v(i + j)));
    }
    return __fadd_rn(
        __fadd_rn(__fadd_rn(r[0], r[1]), __fadd_rn(r[2], r[3])),
        __fadd_rn(__fadd_rn(r[4], r[5]), __fadd_rn(r[6], r[7])));
}

// prep: transpose emb -> et[c][k], se[k] = np.sum(emb[k]^2), zero loss slots
__global__ void prep_kernel(const float* __restrict__ emb,
                            float* __restrict__ se, float* __restrict__ et,
                            float* __restrict__ out) {
    const int tid = blockIdx.x * 256 + threadIdx.x;   // 0..65535
    const int c = tid >> 10, k = tid & 1023;
    et[tid] = emb[k * CCH + c];                        // coalesced write
    if (tid < KCODE) {
        const float* e = emb + (size_t)tid * CCH;
        se[tid] = np_pairwise64_sq([&](int i) { return e[i]; });
    }
    if (tid == 0) { out[LOSS0_OFF] = 0.f; out[LOSS1_OFF] = 0.f; }
}

// main: block = 256 thr = 4 waves; 16 pixels per block.
// R3 restructure: outer-c loop, each thread owns 4 CONSECUTIVE codes (kk=4t..4t+3).
// Per c: one dwordx4 ev load (16B/lane, 1KB/wave) + one s_load_dwordx16 zrow
// + 64 FMAs  =>  4x fewer VMEM and SMEM instructions than the j-outer form,
// and zrow is no longer re-fetched per code group.
// best[]/se/szz deferred to the tail so main-loop live regs ~= acc[64] + misc.
__launch_bounds__(256, 4)
__global__ void vq_kernel(const float* __restrict__ z,
                          const float* __restrict__ emb,
                          const float* __restrict__ se,
                          const float* __restrict__ et,
                          float* __restrict__ out) {
    __shared__ float s_szz[PTILE];
    __shared__ unsigned long long s_cand[PTILE][129];  // halved via shfl pre-reduce; +pad
    __shared__ unsigned long long s_part[PTILE][16];
    __shared__ unsigned int s_k[PTILE];
    __shared__ float s_red[4];

    const int t    = threadIdx.x;
    const int lane = t & 63;
    const int wave = t >> 6;
    const int pg0  = blockIdx.x * PTILE;
    const int b    = pg0 >> 12;
    const int hw0  = pg0 & 4095;
    const float* zb = z + (size_t)b * CCH * HW + hw0;  // zb[c*HW + p], wave-uniform

    // szz for the block's 16 pixels (np order), lanes 0..15 of wave 0
    if (t < PTILE)
        s_szz[t] = np_pairwise64_sq([&](int i) { return zb[(size_t)i * HW + t]; });
    __syncthreads();

    // ---- main accumulation: acc[j][p] = sum_c z[c][p] * E^T[c][4t+j] ----
    float acc[4][PTILE];
#pragma unroll
    for (int j = 0; j < 4; ++j)
#pragma unroll
        for (int p = 0; p < PTILE; ++p) acc[j][p] = 0.f;

    const float* ecol = et + (t << 2);                 // 4 consecutive codes
#pragma unroll 4
    for (int c = 0; c < CCH; ++c) {
        const float4 evv = *reinterpret_cast<const float4*>(ecol + (c << 10));
        const float ev[4] = {evv.x, evv.y, evv.z, evv.w};
        float zrow[PTILE];                              // uniform -> s_load_dwordx16
#pragma unroll
        for (int p = 0; p < PTILE; ++p) zrow[p] = zb[(size_t)c * HW + p];
#pragma unroll
        for (int j = 0; j < 4; ++j)
#pragma unroll
            for (int p = 0; p < PTILE; ++p)
                acc[j][p] = __builtin_fmaf(zrow[p], ev[j], acc[j][p]);  // same chain order as R2
    }

    // ---- finalize distances + per-thread best (tail; acc dies into best) ----
    float szzv[PTILE];
#pragma unroll
    for (int p = 0; p < PTILE; ++p) szzv[p] = s_szz[p];
    const float4 se4v = *reinterpret_cast<const float4*>(se + (t << 2));
    const float se4[4] = {se4v.x, se4v.y, se4v.z, se4v.w};

    unsigned long long best[PTILE];
#pragma unroll
    for (int p = 0; p < PTILE; ++p) best[p] = ~0ULL;

#pragma unroll
    for (int j = 0; j < 4; ++j) {
        const int kk = (t << 2) + j;
#pragma unroll
        for (int p = 0; p < PTILE; ++p) {
            // d = fl( fl(szz+se) - 2*dot )  (identical algebra to R2, absmax 0)
            float d = __fsub_rn(__fadd_rn(szzv[p], se4[j]), __fadd_rn(acc[j][p], acc[j][p]));
            unsigned long long cand =
                ((unsigned long long)__float_as_uint(d) << 32) | (unsigned)kk;
            best[p] = cand < best[p] ? cand : best[p];   // d>0 -> bit-order == value-order
        }
    }

    // stage 1.5: one butterfly step in registers (exact: u64 min over same set),
    // halves the LDS candidate buffer
#pragma unroll
    for (int p = 0; p < PTILE; ++p) {
        unsigned long long o = __shfl_xor(best[p], 1, 64);
        best[p] = o < best[p] ? o : best[p];
    }
    if ((t & 1) == 0) {
#pragma unroll
        for (int p = 0; p < PTILE; ++p) s_cand[p][t >> 1] = best[p];
    }
    __syncthreads();

    {   // stage 2: 256 threads, each folds 8 of the 128 candidates of pixel t&15
        const int p = t & 15, g = t >> 4;
        unsigned long long m = s_cand[p][(g << 3)];
#pragma unroll
        for (int u = 1; u < 8; ++u) {
            unsigned long long v = s_cand[p][(g << 3) + u];
            m = v < m ? v : m;
        }
        s_part[p][g] = m;
    }
    __syncthreads();

    if (t < PTILE) {   // stage 3: final per-pixel min; packed low bits = first-index k
        unsigned long long m = s_part[t][0];
#pragma unroll
        for (int g = 1; g < 16; ++g) {
            unsigned long long v = s_part[t][g];
            m = v < m ? v : m;
        }
        const unsigned int k = (unsigned int)m;
        s_k[t] = k;
        out[IDX_OFF + pg0 + t] = (float)k;
    }
    __syncthreads();

    // epilogue: thread t -> pixel p=t&15, channels c = (t>>4) + 16u
    float lsum = 0.f;
    {
        const int p = t & 15, g = t >> 4;
        const int k = (int)s_k[p];
#pragma unroll
        for (int u = 0; u < 4; ++u) {
            const int c = g + (u << 4);
            float e    = emb[(size_t)k * CCH + c];
            float zc   = zb[(size_t)c * HW + p];
            float diff = __fsub_rn(e, zc);               // STE rounding as in R2
            out[((size_t)(b * CCH + c)) * HW + hw0 + p] = __fadd_rn(zc, diff);
            lsum = __builtin_fmaf(diff, diff, lsum);
        }
    }
#pragma unroll
    for (int off = 32; off > 0; off >>= 1) lsum += __shfl_down(lsum, off, 64);
    if (lane == 0) s_red[wave] = lsum;
    __syncthreads();
    if (t == 0) {
        float v = (s_red[0] + s_red[1] + s_red[2] + s_red[3]) * (1.0f / (float)Q_ELEMS);
        atomicAdd(out + LOSS0_OFF, v);   // codebook_loss
        atomicAdd(out + LOSS1_OFF, v);   // commitment_loss (same forward value)
    }
}

extern "C" void kernel_launch(void* const* d_in, const int* in_sizes, int n_in,
                              void* d_out, int out_size, void* d_ws, size_t ws_size,
                              hipStream_t stream) {
    const float* z   = (const float*)d_in[0];
    const float* emb = (const float*)d_in[1];
    float* out = (float*)d_out;
    float* se  = (float*)d_ws;                 // 1024 floats
    float* et  = se + KCODE;                   // 65536 floats (E^T)

    prep_kernel<<<dim3(256), dim3(256), 0, stream>>>(emb, se, et, out);
    vq_kernel<<<dim3(NPIX / PTILE), dim3(256), 0, stream>>>(z, emb, se, et, out);
}